// Round 2
// baseline (134.021 us; speedup 1.0000x reference)
//
#include <hip/hip_runtime.h>
#include <hip/hip_cooperative_groups.h>

namespace cg = cooperative_groups;

// Problem: x [B=4, L=4096, D=256] fp32. Math reduction: scores are constant
// along the softmax axis -> softmax uniform over causal prefix ->
// out[b,i,:] = mean(x[b,0..i,:]) (causal cumulative mean). q is irrelevant.
//
// Single cooperative kernel, 3 phases separated by grid syncs:
//  (a) each block loads its 8-row chunk into REGISTERS, writes chunk sums P
//  (b) blocks 0..31 build 16-chunk super-sums S (parallel second level)
//  (c) every block sums <=31 S rows + <=15 P rows for its exclusive base,
//      then emits outputs directly from the registers loaded in (a).
// x is read from HBM exactly once; out written once.

#define LL    4096
#define DD4   64          // D/4 (float4 columns per batch)
#define NB    512         // blocks == L-chunks
#define CHUNK 8           // LL / NB rows per block
#define COLS4 256         // (B*D)/4 float4 columns total
#define GSZ   16          // chunks per super-group
#define NGRP  32          // NB / GSZ

__device__ __forceinline__ void f4add(float4& a, const float4 b) {
    a.x += b.x; a.y += b.y; a.z += b.z; a.w += b.w;
}

__global__ __launch_bounds__(256) void cap_fused(const float* __restrict__ x,
                                                 float* __restrict__ out,
                                                 float4* __restrict__ P) {
    float4* S = P + NB * COLS4;           // 2 MiB P, then 128 KiB S, in d_ws
    const int t = threadIdx.x;
    const int c = blockIdx.x;
    const int b = t >> 6, d4 = t & 63;    // thread -> (batch, float4-column)
    const size_t colbase = (size_t)b * LL * DD4 + d4;
    const float4* xb = reinterpret_cast<const float4*>(x) + colbase;
    const int l0 = c * CHUNK;

    // (a) load chunk into registers, coalesced (lanes span consecutive d4)
    float4 v[CHUNK];
    float4 s = {0.f, 0.f, 0.f, 0.f};
#pragma unroll
    for (int k = 0; k < CHUNK; ++k) {
        v[k] = xb[(size_t)(l0 + k) * DD4];
        f4add(s, v[k]);
    }
    P[c * COLS4 + t] = s;

    cg::this_grid().sync();

    // (b) second-level super-sums (parallel; replaces serial scan kernel)
    if (c < NGRP) {
        float4 g = {0.f, 0.f, 0.f, 0.f};
#pragma unroll
        for (int j = 0; j < GSZ; ++j) f4add(g, P[(c * GSZ + j) * COLS4 + t]);
        S[c * COLS4 + t] = g;
    }

    cg::this_grid().sync();

    // (c) exclusive base: full super-groups + remaining chunks
    float4 run = {0.f, 0.f, 0.f, 0.f};
    const int G = c >> 4;                 // c / GSZ
#pragma unroll 4
    for (int g = 0; g < G; ++g) f4add(run, S[g * COLS4 + t]);
#pragma unroll 4
    for (int j = G * GSZ; j < c; ++j) f4add(run, P[j * COLS4 + t]);

    // emit causal means straight from registers (x never re-read)
    float4* ob = reinterpret_cast<float4*>(out) + colbase;
#pragma unroll
    for (int k = 0; k < CHUNK; ++k) {
        f4add(run, v[k]);
        const float inv = 1.0f / (float)(l0 + k + 1);
        float4 o = {run.x * inv, run.y * inv, run.z * inv, run.w * inv};
        ob[(size_t)(l0 + k) * DD4] = o;
    }
}

extern "C" void kernel_launch(void* const* d_in, const int* in_sizes, int n_in,
                              void* d_out, int out_size, void* d_ws, size_t ws_size,
                              hipStream_t stream) {
    const float* x = (const float*)d_in[0];
    // d_in[1] (q) is mathematically irrelevant (softmax of constant row).
    float* out = (float*)d_out;
    float4* P  = (float4*)d_ws;          // needs 2.125 MiB; d_ws is 256 MiB

    void* args[] = { (void*)&x, (void*)&out, (void*)&P };
    hipLaunchCooperativeKernel(reinterpret_cast<void*>(cap_fused),
                               dim3(NB), dim3(256), args, 0, stream);
}

// Round 3
// 21.296 us; speedup vs baseline: 6.2932x; 6.2932x over previous
//
#include <hip/hip_runtime.h>

// Problem: x [B=4, L=4096, D=256] fp32. Math reduction: scores are constant
// along the softmax axis -> softmax uniform over causal prefix ->
// out[b,i,:] = mean(x[b,0..i,:]) (causal cumulative mean). q is irrelevant.
//
// 3 small kernels (round-2 lesson: cooperative grid.sync costs ~50us/sync on
// a 512-block grid -- far more than the 16.8MB x re-read it avoids):
//  K1 cap_sums   512 blk: chunk sums P[512][1024]          (reads x, HBM)
//  K2 cap_groups  32 blk: 16-chunk group sums S[32][1024]  (L2)
//  K3 cap_out    512 blk: 2-level exclusive base (<=31 S + <=15 P rows, L2)
//                + in-chunk running prefix re-reading x (L3-resident), emit.

#define LL    4096
#define DD4   64          // D/4 float4 columns per batch
#define NB    512         // L-chunks
#define CHUNK 8           // LL / NB
#define COLS4 256         // (B*D)/4 float4 columns
#define GSZ   16          // chunks per group
#define NGRP  32          // NB / GSZ

__device__ __forceinline__ void f4add(float4& a, const float4 b) {
    a.x += b.x; a.y += b.y; a.z += b.z; a.w += b.w;
}

// K1: per-chunk column sums. Wave = 64 lanes x float4 = 1 KiB contiguous row
// slice -> perfectly coalesced. 512 blocks x 4 waves = 8 waves/CU.
__global__ __launch_bounds__(256) void cap_sums(const float* __restrict__ x,
                                                float4* __restrict__ P) {
    const int t = threadIdx.x, c = blockIdx.x;
    const int b = t >> 6, d4 = t & 63;
    const float4* xb = reinterpret_cast<const float4*>(x) + (size_t)b * LL * DD4 + d4;
    const int l0 = c * CHUNK;
    float4 s = {0.f, 0.f, 0.f, 0.f};
#pragma unroll
    for (int k = 0; k < CHUNK; ++k) f4add(s, xb[(size_t)(l0 + k) * DD4]);
    P[c * COLS4 + t] = s;
}

// K2: group sums over 16 chunks (parallel; replaces serial scan kernel).
__global__ __launch_bounds__(256) void cap_groups(const float4* __restrict__ P,
                                                  float4* __restrict__ S) {
    const int t = threadIdx.x, g = blockIdx.x;
    float4 s0 = {0.f,0.f,0.f,0.f}, s1 = {0.f,0.f,0.f,0.f};
#pragma unroll
    for (int j = 0; j < GSZ; j += 2) {
        f4add(s0, P[(g * GSZ + j)     * COLS4 + t]);
        f4add(s1, P[(g * GSZ + j + 1) * COLS4 + t]);
    }
    f4add(s0, s1);
    S[g * COLS4 + t] = s0;
}

// K3: exclusive base via 2-level lookback, then emit means.
__global__ __launch_bounds__(256) void cap_out(const float* __restrict__ x,
                                               const float4* __restrict__ P,
                                               const float4* __restrict__ S,
                                               float* __restrict__ out) {
    const int t = threadIdx.x, c = blockIdx.x;
    const int b = t >> 6, d4 = t & 63;
    const size_t colbase = (size_t)b * LL * DD4 + d4;
    const float4* xb = reinterpret_cast<const float4*>(x) + colbase;
    const int l0 = c * CHUNK;

    // issue x loads first (L3-resident) so they overlap the L2 lookback
    float4 v[CHUNK];
#pragma unroll
    for (int k = 0; k < CHUNK; ++k) v[k] = xb[(size_t)(l0 + k) * DD4];

    // exclusive base: full groups (S) + leftover chunks (P), two accumulators
    float4 r0 = {0.f,0.f,0.f,0.f}, r1 = {0.f,0.f,0.f,0.f};
    const int G = c >> 4;                 // c / GSZ
#pragma unroll 4
    for (int g = 0; g + 1 < G; g += 2) {
        f4add(r0, S[g * COLS4 + t]);
        f4add(r1, S[(g + 1) * COLS4 + t]);
    }
    if (G & 1) f4add(r0, S[(G - 1) * COLS4 + t]);
#pragma unroll 4
    for (int j = G * GSZ; j < c; ++j) f4add(r1, P[j * COLS4 + t]);
    float4 run = r0; f4add(run, r1);

    float4* ob = reinterpret_cast<float4*>(out) + colbase;
#pragma unroll
    for (int k = 0; k < CHUNK; ++k) {
        f4add(run, v[k]);
        const float inv = 1.0f / (float)(l0 + k + 1);
        float4 o = {run.x * inv, run.y * inv, run.z * inv, run.w * inv};
        ob[(size_t)(l0 + k) * DD4] = o;
    }
}

extern "C" void kernel_launch(void* const* d_in, const int* in_sizes, int n_in,
                              void* d_out, int out_size, void* d_ws, size_t ws_size,
                              hipStream_t stream) {
    const float* x = (const float*)d_in[0];
    // d_in[1] (q) is mathematically irrelevant (softmax of constant row).
    float* out = (float*)d_out;
    float4* P  = (float4*)d_ws;                 // 512*256*16B = 2 MiB
    float4* S  = P + (size_t)NB * COLS4;        // +128 KiB

    cap_sums  <<<dim3(NB),   dim3(256), 0, stream>>>(x, P);
    cap_groups<<<dim3(NGRP), dim3(256), 0, stream>>>(P, S);
    cap_out   <<<dim3(NB),   dim3(256), 0, stream>>>(x, P, S, out);
}